// Round 4
// baseline (932.560 us; speedup 1.0000x reference)
//
#include <hip/hip_runtime.h>

// RPN target generation for MI355X — single fused kernel.
// Outputs (float32, concat): [0,A) rpn_match; [A,5A) rpn_bbox (A x 4); [5A] num_positives.
// ws layout: [0,2048) gkey (G x u64 packed argmax keys, GLOBAL atomics),
//            [2048] u32 done-counter, [2052] i32 positive count. Pre-zeroed by one memset.
//
// Hot-loop design notes (round-4):
//  - per-gt argmax keys via global_atomic_max (vmcnt domain): the loop has no
//    other VMEM, so atomics are fire-and-forget; DS queue holds only reads.
//    (Round-3 LDS atomics stalled every ds_read behind in-order DS retirement.)
//  - one ds_read_b128 per iter (gt box); garea recomputed in VALU.
//  - iou = inter * rcp(union): branch-free, exact 0 for non-overlap; ~1-ulp
//    vs numpy's IEEE div, harmless under the 2% absmax threshold.

#define GMAX 256

// Faithful to the reference, including the intentional size "bug":
// gt_size = y2 + y1 (not y2 - y1); centre = 0.5 * (y1 + y2).
__device__ __forceinline__ float4 compute_deltas(float4 ab, float4 gb,
                                                 const float* __restrict__ sd) {
    float sy_g = gb.z + gb.x;   // box = (y1, x1, y2, x2) in (x,y,z,w)
    float sx_g = gb.w + gb.y;
    float sy_a = ab.z + ab.x;
    float sx_a = ab.w + ab.y;
    float4 d;
    d.x = (0.5f * (sy_g - sy_a) / sy_a) / sd[0];
    d.y = (0.5f * (sx_g - sx_a) / sx_a) / sd[1];
    d.z = logf(sy_g / sy_a) / sd[2];
    d.w = logf(sx_g / sx_a) / sd[3];
    return d;
}

__global__ __launch_bounds__(256) void rpn_fused(
    const float4* __restrict__ anchors,       // [A]
    const int* __restrict__ valid,            // [A] jnp bool delivered as int32
    const int* __restrict__ cls,              // [G]
    const float4* __restrict__ gt,            // [G]
    const float* __restrict__ stdev,          // [4]
    float* __restrict__ out,                  // [5A+1]
    unsigned long long* __restrict__ gkey,    // [G] in ws, pre-zeroed
    unsigned* __restrict__ done,              // in ws, pre-zeroed
    int* __restrict__ cnt,                    // in ws, pre-zeroed
    int A, int G)
{
    __shared__ float4 s_gt[GMAX];
    __shared__ float s_crowdf[GMAX];          // 1.0 if crowd else 0.0
    __shared__ int s_anycrowd;
    __shared__ int s_cnt;
    __shared__ int s_islast;

    const int tid = threadIdx.x;
    if (tid == 0) { s_anycrowd = 0; s_cnt = 0; }
    if (tid < G) {
        s_gt[tid] = gt[tid];
        int c = cls[tid];
        s_crowdf[tid] = (c < 0) ? 1.0f : 0.0f;
        if (c < 0) s_anycrowd = 1;            // benign race, same value
    }
    __syncthreads();
    const int any_crowd = s_anycrowd;

    const int ai = blockIdx.x * 256 + tid;
    const bool in_range = (ai < A);
    float4 ab = in_range ? anchors[ai] : make_float4(0.f, 0.f, 1.f, 1.f);
    const bool v = in_range && (valid[ai] != 0);
    const float a_area = (ab.z - ab.x) * (ab.w - ab.y);
    const unsigned lokey = 0xFFFFFFFFu - (unsigned)ai;   // smaller ai -> larger lokey

    float best;
    int bg = 0;
    float crowd_max = 0.0f;

    if (!any_crowd) {
        // ---- fast path: no crowd gts ----
        best = -1.0f;                          // all ious >= 0
        #pragma unroll 4
        for (int g = 0; g < G; ++g) {
            float4 gb = s_gt[g];               // ds_read_b128, broadcast
            float y1 = fmaxf(ab.x, gb.x);
            float x1 = fmaxf(ab.y, gb.y);
            float y2 = fminf(ab.z, gb.z);
            float x2 = fminf(ab.w, gb.w);
            float inter = fmaxf(y2 - y1, 0.f) * fmaxf(x2 - x1, 0.f);
            float garea = (gb.z - gb.x) * (gb.w - gb.y);
            float uni = (a_area + garea) - inter;
            float iou = inter * __builtin_amdgcn_rcpf(uni);   // exact 0 if inter==0
            if (iou > best) { best = iou; bg = g; }           // first-index tie-break
            if (v && inter > 0.0f) {
                unsigned long long key =
                    (((unsigned long long)(__float_as_uint(iou) + 1u)) << 32) | lokey;
                atomicMax(&gkey[g], key);      // global atomic: fire-and-forget
            }
        }
    } else {
        // ---- general path: crowd handling (correctness-only) ----
        best = -2.0f;
        for (int g = 0; g < G; ++g) {
            float4 gb = s_gt[g];
            float y1 = fmaxf(ab.x, gb.x);
            float x1 = fmaxf(ab.y, gb.y);
            float y2 = fminf(ab.z, gb.z);
            float x2 = fminf(ab.w, gb.w);
            float inter = fmaxf(y2 - y1, 0.f) * fmaxf(x2 - x1, 0.f);
            float garea = (gb.z - gb.x) * (gb.w - gb.y);
            float uni = (a_area + garea) - inter;
            float iou = inter * __builtin_amdgcn_rcpf(uni);
            float cf = s_crowdf[g];
            float eff = (cf != 0.0f) ? -1.0f : iou;
            if (eff > best) { best = eff; bg = g; }
            crowd_max = fmaxf(crowd_max, iou * cf);
            if (v && (cf == 0.0f) && inter > 0.0f) {
                unsigned long long key =
                    (((unsigned long long)(__float_as_uint(iou) + 1u)) << 32) | lokey;
                atomicMax(&gkey[g], key);
            }
        }
    }

    // provisional positivity (pos_from_gt applied by finalize)
    bool no_crowd = any_crowd ? (crowd_max < 0.001f) : true;
    bool pos = (best >= 0.7f);
    bool neg = (best < 0.3f) && no_crowd && !pos;

    unsigned long long pv = __ballot((int)(in_range && pos && v));
    if ((tid & 63) == 0) atomicAdd(&s_cnt, (int)__popcll(pv));

    if (in_range) {
        out[ai] = v ? (pos ? 1.0f : (neg ? -1.0f : 0.0f)) : 0.0f;
        float4 d = make_float4(0.f, 0.f, 0.f, 0.f);
        if (pos && v) d = compute_deltas(ab, s_gt[bg], stdev);
        ((float4*)(out + A))[ai] = d;
    }
    __syncthreads();

    if (tid == 0 && s_cnt > 0) atomicAdd(cnt, s_cnt);

    // ---- last-block-done: finalize (pos_from_gt scatter + count) ----
    __threadfence();                           // publish out/gkey/cnt device-wide
    if (tid == 0) {
        unsigned prev = atomicAdd(done, 1u);
        s_islast = (prev == gridDim.x - 1);
        s_cnt = 0;                             // reuse as flip counter
    }
    __syncthreads();
    if (!s_islast) return;
    __threadfence();                           // acquire all blocks' writes

    if (tid < G && s_crowdf[tid] == 0.0f) {    // scatter value is False for crowd gts
        unsigned long long key = gkey[tid];
        int w;
        if (key != 0ULL) {
            w = (int)(0xFFFFFFFFu - (unsigned)(key & 0xFFFFFFFFull));
        } else {
            // No valid anchor overlapped this gt: reference argmax picks the first
            // valid anchor (0.0 beats the -1.0 of invalid), or 0 if none valid.
            w = 0;
            for (int i = 0; i < A; ++i) { if (valid[i] != 0) { w = i; break; } }
        }
        if (valid[w] != 0) {
            float old = atomicExch(out + w, 1.0f);   // dedup gts sharing a winner
            if (old != 1.0f) {
                // flip to positive: recompute this anchor's gt-argmax for deltas
                float4 ab2 = anchors[w];
                float a2 = (ab2.z - ab2.x) * (ab2.w - ab2.y);
                float b2 = -2.0f; int g2 = 0;
                for (int g = 0; g < G; ++g) {
                    float4 gb = s_gt[g];
                    float y1 = fmaxf(ab2.x, gb.x);
                    float x1 = fmaxf(ab2.y, gb.y);
                    float y2 = fminf(ab2.z, gb.z);
                    float x2 = fminf(ab2.w, gb.w);
                    float inter = fmaxf(y2 - y1, 0.f) * fmaxf(x2 - x1, 0.f);
                    float garea = (gb.z - gb.x) * (gb.w - gb.y);
                    float uni = (a2 + garea) - inter;
                    float iou = inter * __builtin_amdgcn_rcpf(uni);
                    float eff = (s_crowdf[g] != 0.0f) ? -1.0f : iou;
                    if (eff > b2) { b2 = eff; g2 = g; }
                }
                ((float4*)(out + A))[w] = compute_deltas(ab2, s_gt[g2], stdev);
                atomicAdd(&s_cnt, 1);
            }
        }
    }
    __syncthreads();
    if (tid == 0) out[(size_t)5 * A] = (float)(*cnt + s_cnt);
}

extern "C" void kernel_launch(void* const* d_in, const int* in_sizes, int n_in,
                              void* d_out, int out_size, void* d_ws, size_t ws_size,
                              hipStream_t stream) {
    const float4* anchors = (const float4*)d_in[0];
    const int* valid      = (const int*)d_in[1];   // jnp bool -> int32 per element
    const int* cls        = (const int*)d_in[2];
    const float4* gt      = (const float4*)d_in[3];
    const float* stdev    = (const float*)d_in[4];
    float* out            = (float*)d_out;

    const int A = in_sizes[0] / 4;
    const int G = in_sizes[2];                 // 256

    unsigned long long* gkey = (unsigned long long*)d_ws;
    unsigned* done = (unsigned*)((char*)d_ws + 2048);
    int* cnt       = (int*)((char*)d_ws + 2052);
    hipMemsetAsync(d_ws, 0, 2056, stream);

    const int blocks = (A + 255) / 256;        // 1023 for A=261888
    rpn_fused<<<blocks, 256, 0, stream>>>(anchors, valid, cls, gt, stdev, out,
                                          gkey, done, cnt, A, G);
}

// Round 5
// 182.858 us; speedup vs baseline: 5.0999x; 5.0999x over previous
//
#include <hip/hip_runtime.h>

// RPN target generation for MI355X — single fused kernel.
// Outputs (float32, concat): [0,A) rpn_match; [A,5A) rpn_bbox (A x 4); [5A] num_positives.
// ws layout: [0,2048) gkey (G x u64 packed argmax keys), [2048] u32 done-counter,
//            [2052] i32 positive count. Pre-zeroed by one memset.
//
// Reduction design (round-5): the per-gt argmax must touch NO shared resource in
// the A*G hot loop. R2 (shfl reduce) = ds_bpermute spam; R3 (LDS atomic/iter) =
// DS-queue stalls; R4 (global atomic/iter) = memory-side atomic meltdown
// (WRITE_SIZE +21MB). Here: per-lane 256-bit overlap bitmask in VGPRs (~4
// VALU/iter), then a post-loop sparse drain (~5 bits/lane) recomputes those
// IoUs and does rare LDS atomicMax, then one block-level merge to global gkey.

#define GMAX 256

// Faithful to the reference, including the intentional size "bug":
// gt_size = y2 + y1 (not y2 - y1); centre = 0.5 * (y1 + y2).
__device__ __forceinline__ float4 compute_deltas(float4 ab, float4 gb,
                                                 const float* __restrict__ sd) {
    float sy_g = gb.z + gb.x;   // box = (y1, x1, y2, x2) in (x,y,z,w)
    float sx_g = gb.w + gb.y;
    float sy_a = ab.z + ab.x;
    float sx_a = ab.w + ab.y;
    float4 d;
    d.x = (0.5f * (sy_g - sy_a) / sy_a) / sd[0];
    d.y = (0.5f * (sx_g - sx_a) / sx_a) / sd[1];
    d.z = logf(sy_g / sy_a) / sd[2];
    d.w = logf(sx_g / sx_a) / sd[3];
    return d;
}

__device__ __forceinline__ float iou_of(float4 ab, float a_area, float4 gb) {
    float y1 = fmaxf(ab.x, gb.x);
    float x1 = fmaxf(ab.y, gb.y);
    float y2 = fminf(ab.z, gb.z);
    float x2 = fminf(ab.w, gb.w);
    float inter = fmaxf(y2 - y1, 0.f) * fmaxf(x2 - x1, 0.f);
    float garea = (gb.z - gb.x) * (gb.w - gb.y);
    float uni = (a_area + garea) - inter;
    return inter * __builtin_amdgcn_rcpf(uni);   // exact 0 if inter==0
}

__global__ __launch_bounds__(256) void rpn_fused(
    const float4* __restrict__ anchors,       // [A]
    const int* __restrict__ valid,            // [A] jnp bool delivered as int32
    const int* __restrict__ cls,              // [G]
    const float4* __restrict__ gt,            // [G]
    const float* __restrict__ stdev,          // [4]
    float* __restrict__ out,                  // [5A+1]
    unsigned long long* __restrict__ gkey,    // [G] in ws, pre-zeroed
    unsigned* __restrict__ done,              // in ws, pre-zeroed
    int* __restrict__ cnt,                    // in ws, pre-zeroed
    int A, int G)
{
    __shared__ float4 s_gt[GMAX];
    __shared__ float s_crowdf[GMAX];          // 1.0 if crowd else 0.0
    __shared__ unsigned long long s_key[GMAX];
    __shared__ int s_anycrowd;
    __shared__ int s_cnt;
    __shared__ int s_islast;

    const int tid = threadIdx.x;
    if (tid == 0) { s_anycrowd = 0; s_cnt = 0; }
    if (tid < G) {
        s_gt[tid] = gt[tid];
        int c = cls[tid];
        s_crowdf[tid] = (c < 0) ? 1.0f : 0.0f;
        if (c < 0) s_anycrowd = 1;            // benign race, same value
        s_key[tid] = 0ULL;
    }
    __syncthreads();
    const int any_crowd = s_anycrowd;

    const int ai = blockIdx.x * 256 + tid;
    const bool in_range = (ai < A);
    float4 ab = in_range ? anchors[ai] : make_float4(0.f, 0.f, 1.f, 1.f);
    const bool v = in_range && (valid[ai] != 0);
    const float a_area = (ab.z - ab.x) * (ab.w - ab.y);
    const unsigned lokey = 0xFFFFFFFFu - (unsigned)ai;   // smaller ai -> larger lokey

    float best;
    int bg = 0;
    float crowd_max = 0.0f;
    unsigned long long ovmask[4];             // statically indexed (outer unroll)

    if (!any_crowd) {
        // ---- fast path: no crowd gts ----
        best = -1.0f;                          // all ious >= 0
        #pragma unroll
        for (int w = 0; w < 4; ++w) {
            unsigned long long m = 0ULL;
            #pragma unroll 4
            for (int j = 0; j < 64; ++j) {
                int g = (w << 6) + j;
                float4 gb = s_gt[g];           // ds_read_b128, broadcast
                float y1 = fmaxf(ab.x, gb.x);
                float x1 = fmaxf(ab.y, gb.y);
                float y2 = fminf(ab.z, gb.z);
                float x2 = fminf(ab.w, gb.w);
                float inter = fmaxf(y2 - y1, 0.f) * fmaxf(x2 - x1, 0.f);
                float garea = (gb.z - gb.x) * (gb.w - gb.y);
                float uni = (a_area + garea) - inter;
                float iou = inter * __builtin_amdgcn_rcpf(uni);
                if (iou > best) { best = iou; bg = g; }       // first-index tie-break
                if (v && inter > 0.0f) m |= (1ULL << j);      // uniform shift (SALU)
            }
            ovmask[w] = m;
        }
    } else {
        // ---- general path: crowd handling (correctness-only) ----
        best = -2.0f;
        #pragma unroll
        for (int w = 0; w < 4; ++w) {
            unsigned long long m = 0ULL;
            for (int j = 0; j < 64; ++j) {
                int g = (w << 6) + j;
                float4 gb = s_gt[g];
                float y1 = fmaxf(ab.x, gb.x);
                float x1 = fmaxf(ab.y, gb.y);
                float y2 = fminf(ab.z, gb.z);
                float x2 = fminf(ab.w, gb.w);
                float inter = fmaxf(y2 - y1, 0.f) * fmaxf(x2 - x1, 0.f);
                float garea = (gb.z - gb.x) * (gb.w - gb.y);
                float uni = (a_area + garea) - inter;
                float iou = inter * __builtin_amdgcn_rcpf(uni);
                float cf = s_crowdf[g];
                float eff = (cf != 0.0f) ? -1.0f : iou;
                if (eff > best) { best = eff; bg = g; }
                crowd_max = fmaxf(crowd_max, iou * cf);
                if (v && (cf == 0.0f) && inter > 0.0f) m |= (1ULL << j);
            }
            ovmask[w] = m;
        }
    }

    // ---- sparse drain: ~5 set bits per lane -> LDS atomicMax into s_key ----
    #pragma unroll
    for (int w = 0; w < 4; ++w) {
        unsigned long long m = ovmask[w];
        while (m != 0ULL) {
            int j = __builtin_ctzll(m);
            m &= (m - 1ULL);
            int g = (w << 6) + j;
            float iou = iou_of(ab, a_area, s_gt[g]);   // divergent ds_read (rare)
            unsigned long long key =
                (((unsigned long long)(__float_as_uint(iou) + 1u)) << 32) | lokey;
            atomicMax(&s_key[g], key);
        }
    }

    // provisional positivity (pos_from_gt applied by finalize)
    bool no_crowd = any_crowd ? (crowd_max < 0.001f) : true;
    bool pos = (best >= 0.7f);
    bool neg = (best < 0.3f) && no_crowd && !pos;

    unsigned long long pv = __ballot((int)(in_range && pos && v));
    if ((tid & 63) == 0) atomicAdd(&s_cnt, (int)__popcll(pv));

    if (in_range) {
        out[ai] = v ? (pos ? 1.0f : (neg ? -1.0f : 0.0f)) : 0.0f;
        float4 d = make_float4(0.f, 0.f, 0.f, 0.f);
        if (pos && v) d = compute_deltas(ab, s_gt[bg], stdev);
        ((float4*)(out + A))[ai] = d;
    }
    __syncthreads();

    // block-level merge: only gts someone in this block overlapped (~30/block)
    if (tid < G && s_key[tid] != 0ULL) atomicMax(&gkey[tid], s_key[tid]);
    if (tid == 0 && s_cnt > 0) atomicAdd(cnt, s_cnt);

    // ---- last-block-done: finalize (pos_from_gt scatter + count) ----
    __threadfence();                           // publish out/gkey/cnt device-wide
    if (tid == 0) {
        unsigned prev = atomicAdd(done, 1u);
        s_islast = (prev == gridDim.x - 1);
        s_cnt = 0;                             // reuse as flip counter
    }
    __syncthreads();
    if (!s_islast) return;
    __threadfence();                           // acquire all blocks' writes

    if (tid < G && s_crowdf[tid] == 0.0f) {    // scatter value is False for crowd gts
        unsigned long long key = gkey[tid];
        int w;
        if (key != 0ULL) {
            w = (int)(0xFFFFFFFFu - (unsigned)(key & 0xFFFFFFFFull));
        } else {
            // No valid anchor overlapped this gt: reference argmax picks the first
            // valid anchor (0.0 beats the -1.0 of invalid), or 0 if none valid.
            w = 0;
            for (int i = 0; i < A; ++i) { if (valid[i] != 0) { w = i; break; } }
        }
        if (valid[w] != 0) {
            float old = atomicExch(out + w, 1.0f);   // dedup gts sharing a winner
            if (old != 1.0f) {
                // flip to positive: recompute this anchor's gt-argmax for deltas
                float4 ab2 = anchors[w];
                float a2 = (ab2.z - ab2.x) * (ab2.w - ab2.y);
                float b2 = -2.0f; int g2 = 0;
                for (int g = 0; g < G; ++g) {
                    float iou = iou_of(ab2, a2, s_gt[g]);
                    float eff = (s_crowdf[g] != 0.0f) ? -1.0f : iou;
                    if (eff > b2) { b2 = eff; g2 = g; }
                }
                ((float4*)(out + A))[w] = compute_deltas(ab2, s_gt[g2], stdev);
                atomicAdd(&s_cnt, 1);
            }
        }
    }
    __syncthreads();
    if (tid == 0) out[(size_t)5 * A] = (float)(*cnt + s_cnt);
}

extern "C" void kernel_launch(void* const* d_in, const int* in_sizes, int n_in,
                              void* d_out, int out_size, void* d_ws, size_t ws_size,
                              hipStream_t stream) {
    const float4* anchors = (const float4*)d_in[0];
    const int* valid      = (const int*)d_in[1];   // jnp bool -> int32 per element
    const int* cls        = (const int*)d_in[2];
    const float4* gt      = (const float4*)d_in[3];
    const float* stdev    = (const float*)d_in[4];
    float* out            = (float*)d_out;

    const int A = in_sizes[0] / 4;
    const int G = in_sizes[2];                 // 256

    unsigned long long* gkey = (unsigned long long*)d_ws;
    unsigned* done = (unsigned*)((char*)d_ws + 2048);
    int* cnt       = (int*)((char*)d_ws + 2052);
    hipMemsetAsync(d_ws, 0, 2056, stream);

    const int blocks = (A + 255) / 256;        // 1023 for A=261888
    rpn_fused<<<blocks, 256, 0, stream>>>(anchors, valid, cls, gt, stdev, out,
                                          gkey, done, cnt, A, G);
}